// Round 2
// baseline (4375.975 us; speedup 1.0000x reference)
//
#include <hip/hip_runtime.h>

#define N_NODES 102000
#define D 128
#define L 12
#define E_EDGES 1000000
#define NEG_SLOPE 0.01f

// ---------------------------------------------------------------------------
// 1) h[n] = sum_l word_emb[wids[n][l]] / lengths[n]
//    thread = (node, 4-feature chunk); float4 gathers, coalesced stores
// ---------------------------------------------------------------------------
__global__ void pool_kernel(const int* __restrict__ wids,
                            const float* __restrict__ lengths,
                            const float* __restrict__ word_emb,
                            float* __restrict__ h) {
    int idx = blockIdx.x * blockDim.x + threadIdx.x;
    int n = idx >> 5, q = idx & 31;
    if (n >= N_NODES) return;
    const int* w = wids + n * L;
    float4 acc = make_float4(0.f, 0.f, 0.f, 0.f);
#pragma unroll
    for (int l = 0; l < L; ++l) {
        int wid = w[l];
        const float4 v = *reinterpret_cast<const float4*>(word_emb + (size_t)wid * D + q * 4);
        acc.x += v.x; acc.y += v.y; acc.z += v.z; acc.w += v.w;
    }
    float inv = 1.0f / lengths[n];
    acc.x *= inv; acc.y *= inv; acc.z *= inv; acc.w *= inv;
    *reinterpret_cast<float4*>(h + (size_t)n * D + q * 4) = acc;
}

// ---------------------------------------------------------------------------
// 2) deg[n] = #in-edges (as float; exact for counts < 2^24)
// ---------------------------------------------------------------------------
__global__ void deg_kernel(const int* __restrict__ dst, float* __restrict__ deg) {
    int e = blockIdx.x * blockDim.x + threadIdx.x;
    if (e < E_EDGES) atomicAdd(&deg[dst[e]], 1.0f);
}

// ---------------------------------------------------------------------------
// 3) agg[dst[e]] += h[src[e]]  (scatter-add, 4 scalar atomics per thread)
// ---------------------------------------------------------------------------
__global__ void agg_kernel(const int* __restrict__ src, const int* __restrict__ dst,
                           const float* __restrict__ h, float* __restrict__ agg) {
    long long idx = (long long)blockIdx.x * blockDim.x + threadIdx.x;
    int e = (int)(idx >> 5), q = (int)(idx & 31);
    if (e >= E_EDGES) return;
    int s = src[e], t = dst[e];
    float4 v = *reinterpret_cast<const float4*>(h + (size_t)s * D + q * 4);
    float* p = agg + (size_t)t * D + q * 4;
    atomicAdd(p + 0, v.x);
    atomicAdd(p + 1, v.y);
    atomicAdd(p + 2, v.z);
    atomicAdd(p + 3, v.w);
}

// ---------------------------------------------------------------------------
// 4) out[n] = hin[n] @ Wself + (agg[n]/max(deg,1)) @ Wneigh + b  (+leaky relu)
//    Both W in LDS (128 KB -> 1 block/CU). Each thread: 4 rows x 1 col.
//    In-place (out == hin) is safe ONLY with the barrier: a tile's rows are
//    read by two waves (rg group spans 128 threads) — all loads of the tile
//    must complete block-wide before any store to it.
// ---------------------------------------------------------------------------
template <int RELU>
__global__ __launch_bounds__(256, 1)
void linear_kernel(const float* __restrict__ hin, const float* __restrict__ agg,
                   const float* __restrict__ deg,
                   const float* __restrict__ Wself, const float* __restrict__ Wneigh,
                   const float* __restrict__ bias, float* __restrict__ out) {
    __shared__ float sWs[D * D];
    __shared__ float sWn[D * D];
    __shared__ float sb[D];
    int t = threadIdx.x;
    {
        const float4* ws4 = (const float4*)Wself;
        const float4* wn4 = (const float4*)Wneigh;
        float4* ds4 = (float4*)sWs;
        float4* dn4 = (float4*)sWn;
        for (int i = t; i < D * D / 4; i += 256) { ds4[i] = ws4[i]; dn4[i] = wn4[i]; }
        if (t < D) sb[t] = bias[t];
    }
    __syncthreads();

    int d = t & 127;
    int rg = t >> 7;  // 0 or 1
    const int TILES = N_NODES / 8;  // 12750 (exact)
    for (int tile = blockIdx.x; tile < TILES; tile += gridDim.x) {
        int row0 = tile * 8 + rg * 4;
        float acc[4], accn[4];
#pragma unroll
        for (int r = 0; r < 4; ++r) { acc[r] = 0.f; accn[r] = 0.f; }
        const float4* h4 = (const float4*)(hin + (size_t)row0 * D);
        const float4* a4 = (const float4*)(agg + (size_t)row0 * D);
#pragma unroll
        for (int k4 = 0; k4 < 32; ++k4) {
            float4 hv[4], av[4];
#pragma unroll
            for (int r = 0; r < 4; ++r) {
                hv[r] = h4[r * 32 + k4];
                av[r] = a4[r * 32 + k4];
            }
#pragma unroll
            for (int j = 0; j < 4; ++j) {
                int k = k4 * 4 + j;
                float wjs = sWs[k * D + d];
                float wjn = sWn[k * D + d];
#pragma unroll
                for (int r = 0; r < 4; ++r) {
                    float hj = (&hv[r].x)[j];
                    float aj = (&av[r].x)[j];
                    acc[r] += hj * wjs;
                    accn[r] += aj * wjn;
                }
            }
        }
        // All loads of this tile's rows (hin + agg) are now done thread-locally;
        // barrier makes that true block-wide before anyone overwrites hin rows.
        __syncthreads();
#pragma unroll
        for (int r = 0; r < 4; ++r) {
            int row = row0 + r;
            float sc = 1.0f / fmaxf(deg[row], 1.0f);
            float v = acc[r] + accn[r] * sc + sb[d];
            if (RELU) v = (v > 0.f) ? v : NEG_SLOPE * v;
            out[(size_t)row * D + d] = v;
        }
    }
}

extern "C" void kernel_launch(void* const* d_in, const int* in_sizes, int n_in,
                              void* d_out, int out_size, void* d_ws, size_t ws_size,
                              hipStream_t stream) {
    const int*   wids     = (const int*)d_in[0];
    const float* lengths  = (const float*)d_in[1];
    const int*   src      = (const int*)d_in[2];
    const int*   dst      = (const int*)d_in[3];
    const float* word_emb = (const float*)d_in[4];
    const float* W1s      = (const float*)d_in[5];
    const float* W1n      = (const float*)d_in[6];
    const float* b1       = (const float*)d_in[7];
    const float* W2s      = (const float*)d_in[8];
    const float* W2n      = (const float*)d_in[9];
    const float* b2       = (const float*)d_in[10];
    float* out = (float*)d_out;

    float* agg = (float*)d_ws;                      // N*D floats
    float* deg = agg + (size_t)N_NODES * D;         // N floats

    // zero agg + deg (contiguous)
    hipMemsetAsync(agg, 0, ((size_t)N_NODES * D + N_NODES) * sizeof(float), stream);

    // h -> d_out
    pool_kernel<<<(N_NODES * 32) / 256, 256, 0, stream>>>(wids, lengths, word_emb, out);
    // degree
    deg_kernel<<<(E_EDGES + 255) / 256, 256, 0, stream>>>(dst, deg);
    // layer-1 aggregate: agg = sum h[src] by dst
    agg_kernel<<<(E_EDGES * 32) / 256, 256, 0, stream>>>(src, dst, out, agg);
    // layer-1 linear (+leaky relu), in-place into d_out
    linear_kernel<1><<<256, 256, 0, stream>>>(out, agg, deg, W1s, W1n, b1, out);
    // layer-2 aggregate
    hipMemsetAsync(agg, 0, (size_t)N_NODES * D * sizeof(float), stream);
    agg_kernel<<<(E_EDGES * 32) / 256, 256, 0, stream>>>(src, dst, out, agg);
    // layer-2 linear, in-place into d_out
    linear_kernel<0><<<256, 256, 0, stream>>>(out, agg, deg, W2s, W2n, b2, out);
}

// Round 3
// 1303.355 us; speedup vs baseline: 3.3575x; 3.3575x over previous
//
#include <hip/hip_runtime.h>

#define N_NODES 102000
#define D 128
#define L 12
#define E_EDGES 1000000
#define NEG_SLOPE 0.01f

// ---------------------------------------------------------------------------
// 1) h[n] = sum_l word_emb[wids[n][l]] / lengths[n]
// ---------------------------------------------------------------------------
__global__ void pool_kernel(const int* __restrict__ wids,
                            const float* __restrict__ lengths,
                            const float* __restrict__ word_emb,
                            float* __restrict__ h) {
    int idx = blockIdx.x * blockDim.x + threadIdx.x;
    int n = idx >> 5, q = idx & 31;
    if (n >= N_NODES) return;
    const int* w = wids + n * L;
    float4 acc = make_float4(0.f, 0.f, 0.f, 0.f);
#pragma unroll
    for (int l = 0; l < L; ++l) {
        int wid = w[l];
        const float4 v = *reinterpret_cast<const float4*>(word_emb + (size_t)wid * D + q * 4);
        acc.x += v.x; acc.y += v.y; acc.z += v.z; acc.w += v.w;
    }
    float inv = 1.0f / lengths[n];
    acc.x *= inv; acc.y *= inv; acc.z *= inv; acc.w *= inv;
    *reinterpret_cast<float4*>(h + (size_t)n * D + q * 4) = acc;
}

// ---------------------------------------------------------------------------
// 2) int degree histogram
// ---------------------------------------------------------------------------
__global__ void degi_kernel(const int* __restrict__ dst, int* __restrict__ deg) {
    int e = blockIdx.x * blockDim.x + threadIdx.x;
    if (e < E_EDGES) atomicAdd(&deg[dst[e]], 1);
}

// ---------------------------------------------------------------------------
// 3) exclusive scan of deg -> row_ptr (and cursor copy). Single block, 1024
//    threads, wave-shuffle scan + LDS wave-sum scan. ~100 chunks.
// ---------------------------------------------------------------------------
__global__ __launch_bounds__(1024)
void scan_kernel(const int* __restrict__ deg, int* __restrict__ row_ptr,
                 int* __restrict__ cursor) {
    __shared__ int wsum[16];
    __shared__ int s_base;
    int t = threadIdx.x;
    int lane = t & 63, w = t >> 6;
    if (t == 0) s_base = 0;
    __syncthreads();
    for (int start = 0; start < N_NODES; start += 1024) {
        int i = start + t;
        int v = (i < N_NODES) ? deg[i] : 0;
        // inclusive wave scan
        int x = v;
#pragma unroll
        for (int off = 1; off < 64; off <<= 1) {
            int y = __shfl_up(x, off, 64);
            if (lane >= off) x += y;
        }
        if (lane == 63) wsum[w] = x;
        __syncthreads();
        if (w == 0 && lane < 16) {
            int s = wsum[lane];
#pragma unroll
            for (int off = 1; off < 16; off <<= 1) {
                int y = __shfl_up(s, off, 64);
                if (lane >= off) s += y;
            }
            wsum[lane] = s;  // inclusive scan of wave sums
        }
        __syncthreads();
        int wave_excl = (w == 0) ? 0 : wsum[w - 1];
        int excl = s_base + wave_excl + (x - v);
        if (i < N_NODES) { row_ptr[i] = excl; cursor[i] = excl; }
        __syncthreads();                    // all reads of s_base/wsum done
        if (t == 0) s_base += wsum[15];
        __syncthreads();                    // update visible before next chunk
    }
    if (t == 0) row_ptr[N_NODES] = s_base;
}

// ---------------------------------------------------------------------------
// 4) scatter edges into CSR slots (1M int atomics; intra-row order is
//    nondeterministic but only perturbs f32 rounding ~1e-6, far below thr)
// ---------------------------------------------------------------------------
__global__ void scatter_kernel(const int* __restrict__ src, const int* __restrict__ dst,
                               int* __restrict__ cursor, int* __restrict__ csr_src) {
    int e = blockIdx.x * blockDim.x + threadIdx.x;
    if (e < E_EDGES) {
        int pos = atomicAdd(&cursor[dst[e]], 1);
        csr_src[pos] = src[e];
    }
}

// ---------------------------------------------------------------------------
// 5) gather-aggregate: aggn[n] = mean_{s in N_in(n)} h[s]  (normalized here)
//    thread = (node, float4 chunk); coalesced row gathers, plain stores
// ---------------------------------------------------------------------------
__global__ void gather_agg_kernel(const int* __restrict__ row_ptr,
                                  const int* __restrict__ csr_src,
                                  const float* __restrict__ h,
                                  float* __restrict__ aggn) {
    int idx = blockIdx.x * blockDim.x + threadIdx.x;
    int n = idx >> 5, q = idx & 31;
    if (n >= N_NODES) return;
    int beg = row_ptr[n], end = row_ptr[n + 1];
    float4 acc = make_float4(0.f, 0.f, 0.f, 0.f);
    for (int p = beg; p < end; ++p) {
        int s = csr_src[p];
        const float4 v = *reinterpret_cast<const float4*>(h + (size_t)s * D + q * 4);
        acc.x += v.x; acc.y += v.y; acc.z += v.z; acc.w += v.w;
    }
    int dcount = end - beg;
    float inv = 1.0f / (float)(dcount > 1 ? dcount : 1);
    acc.x *= inv; acc.y *= inv; acc.z *= inv; acc.w *= inv;
    *reinterpret_cast<float4*>(aggn + (size_t)n * D + q * 4) = acc;
}

// ---------------------------------------------------------------------------
// 6) out[n] = hin[n] @ Wself + aggn[n] @ Wneigh + b  (+leaky relu)
//    In-place safe only with the block-wide barrier before stores.
// ---------------------------------------------------------------------------
template <int RELU>
__global__ __launch_bounds__(256, 1)
void linear_kernel(const float* __restrict__ hin, const float* __restrict__ aggn,
                   const float* __restrict__ Wself, const float* __restrict__ Wneigh,
                   const float* __restrict__ bias, float* __restrict__ out) {
    __shared__ float sWs[D * D];
    __shared__ float sWn[D * D];
    __shared__ float sb[D];
    int t = threadIdx.x;
    {
        const float4* ws4 = (const float4*)Wself;
        const float4* wn4 = (const float4*)Wneigh;
        float4* ds4 = (float4*)sWs;
        float4* dn4 = (float4*)sWn;
        for (int i = t; i < D * D / 4; i += 256) { ds4[i] = ws4[i]; dn4[i] = wn4[i]; }
        if (t < D) sb[t] = bias[t];
    }
    __syncthreads();

    int d = t & 127;
    int rg = t >> 7;  // 0 or 1
    const int TILES = N_NODES / 8;  // 12750 (exact)
    for (int tile = blockIdx.x; tile < TILES; tile += gridDim.x) {
        int row0 = tile * 8 + rg * 4;
        float acc[4], accn[4];
#pragma unroll
        for (int r = 0; r < 4; ++r) { acc[r] = 0.f; accn[r] = 0.f; }
        const float4* h4 = (const float4*)(hin + (size_t)row0 * D);
        const float4* a4 = (const float4*)(aggn + (size_t)row0 * D);
#pragma unroll
        for (int k4 = 0; k4 < 32; ++k4) {
            float4 hv[4], av[4];
#pragma unroll
            for (int r = 0; r < 4; ++r) {
                hv[r] = h4[r * 32 + k4];
                av[r] = a4[r * 32 + k4];
            }
#pragma unroll
            for (int j = 0; j < 4; ++j) {
                int k = k4 * 4 + j;
                float wjs = sWs[k * D + d];
                float wjn = sWn[k * D + d];
#pragma unroll
                for (int r = 0; r < 4; ++r) {
                    acc[r]  += (&hv[r].x)[j] * wjs;
                    accn[r] += (&av[r].x)[j] * wjn;
                }
            }
        }
        __syncthreads();  // all loads of this tile done block-wide before stores
#pragma unroll
        for (int r = 0; r < 4; ++r) {
            int row = row0 + r;
            float v = acc[r] + accn[r] + sb[d];
            if (RELU) v = (v > 0.f) ? v : NEG_SLOPE * v;
            out[(size_t)row * D + d] = v;
        }
    }
}

extern "C" void kernel_launch(void* const* d_in, const int* in_sizes, int n_in,
                              void* d_out, int out_size, void* d_ws, size_t ws_size,
                              hipStream_t stream) {
    const int*   wids     = (const int*)d_in[0];
    const float* lengths  = (const float*)d_in[1];
    const int*   src      = (const int*)d_in[2];
    const int*   dst      = (const int*)d_in[3];
    const float* word_emb = (const float*)d_in[4];
    const float* W1s      = (const float*)d_in[5];
    const float* W1n      = (const float*)d_in[6];
    const float* b1       = (const float*)d_in[7];
    const float* W2s      = (const float*)d_in[8];
    const float* W2n      = (const float*)d_in[9];
    const float* b2       = (const float*)d_in[10];
    float* out = (float*)d_out;

    // workspace layout
    float* aggn    = (float*)d_ws;                            // N*D f32
    int*   deg_i   = (int*)(aggn + (size_t)N_NODES * D);      // N
    int*   row_ptr = deg_i + N_NODES;                         // N+1
    int*   cursor  = row_ptr + (N_NODES + 1);                 // N
    int*   csr_src = cursor + N_NODES;                        // E

    // zero the degree histogram only (everything else is fully overwritten)
    hipMemsetAsync(deg_i, 0, N_NODES * sizeof(int), stream);

    // h -> d_out
    pool_kernel<<<(N_NODES * 32) / 256, 256, 0, stream>>>(wids, lengths, word_emb, out);

    // CSR build (shared by both layers)
    degi_kernel<<<(E_EDGES + 255) / 256, 256, 0, stream>>>(dst, deg_i);
    scan_kernel<<<1, 1024, 0, stream>>>(deg_i, row_ptr, cursor);
    scatter_kernel<<<(E_EDGES + 255) / 256, 256, 0, stream>>>(src, dst, cursor, csr_src);

    // layer 1
    gather_agg_kernel<<<(N_NODES * 32) / 256, 256, 0, stream>>>(row_ptr, csr_src, out, aggn);
    linear_kernel<1><<<256, 256, 0, stream>>>(out, aggn, W1s, W1n, b1, out);
    // layer 2
    gather_agg_kernel<<<(N_NODES * 32) / 256, 256, 0, stream>>>(row_ptr, csr_src, out, aggn);
    linear_kernel<0><<<256, 256, 0, stream>>>(out, aggn, W2s, W2n, b2, out);
}

// Round 4
// 433.761 us; speedup vs baseline: 10.0884x; 3.0048x over previous
//
#include <hip/hip_runtime.h>

#define N_NODES 102000
#define D 128
#define L 12
#define E_EDGES 1000000
#define NEG_SLOPE 0.01f
#define NTILES (N_NODES / 16)   // 6375 exact (N % 16 == 0)

typedef __attribute__((ext_vector_type(8))) short bf16x8;
typedef __attribute__((ext_vector_type(4))) float f32x4;

__device__ __forceinline__ float b2f(unsigned short u) {
    union { float f; unsigned int i; } x; x.i = ((unsigned int)u) << 16; return x.f;
}
// round-to-nearest-even f32 -> bf16
__device__ __forceinline__ unsigned short f2b(float f) {
    unsigned int x = __float_as_uint(f);
    unsigned int r = (x + 0x7fffu + ((x >> 16) & 1u)) >> 16;
    return (unsigned short)r;
}

// ---------------------------------------------------------------------------
// 1) h[n] = sum_l word_emb[wids[n][l]] / lengths[n]   (f32 acc -> bf16 store)
// ---------------------------------------------------------------------------
__global__ void pool_kernel(const int* __restrict__ wids,
                            const float* __restrict__ lengths,
                            const float* __restrict__ word_emb,
                            unsigned short* __restrict__ hb) {
    int idx = blockIdx.x * blockDim.x + threadIdx.x;
    int n = idx >> 5, q = idx & 31;
    if (n >= N_NODES) return;
    const int* w = wids + n * L;
    float4 acc = make_float4(0.f, 0.f, 0.f, 0.f);
#pragma unroll
    for (int l = 0; l < L; ++l) {
        int wid = w[l];
        const float4 v = *reinterpret_cast<const float4*>(word_emb + (size_t)wid * D + q * 4);
        acc.x += v.x; acc.y += v.y; acc.z += v.z; acc.w += v.w;
    }
    float inv = 1.0f / lengths[n];
    ushort4 o;
    o.x = f2b(acc.x * inv); o.y = f2b(acc.y * inv);
    o.z = f2b(acc.z * inv); o.w = f2b(acc.w * inv);
    *reinterpret_cast<ushort4*>(hb + (size_t)n * D + q * 4) = o;
}

// ---------------------------------------------------------------------------
// 2) int degree histogram
// ---------------------------------------------------------------------------
__global__ void degi_kernel(const int* __restrict__ dst, int* __restrict__ deg) {
    int e = blockIdx.x * blockDim.x + threadIdx.x;
    if (e < E_EDGES) atomicAdd(&deg[dst[e]], 1);
}

// ---------------------------------------------------------------------------
// 3) exclusive scan of deg -> row_ptr (+cursor copy). Single 1024-thr block.
// ---------------------------------------------------------------------------
__global__ __launch_bounds__(1024)
void scan_kernel(const int* __restrict__ deg, int* __restrict__ row_ptr,
                 int* __restrict__ cursor) {
    __shared__ int wsum[16];
    __shared__ int s_base;
    int t = threadIdx.x;
    int lane = t & 63, w = t >> 6;
    if (t == 0) s_base = 0;
    __syncthreads();
    for (int start = 0; start < N_NODES; start += 1024) {
        int i = start + t;
        int v = (i < N_NODES) ? deg[i] : 0;
        int x = v;
#pragma unroll
        for (int off = 1; off < 64; off <<= 1) {
            int y = __shfl_up(x, off, 64);
            if (lane >= off) x += y;
        }
        if (lane == 63) wsum[w] = x;
        __syncthreads();
        if (w == 0 && lane < 16) {
            int s = wsum[lane];
#pragma unroll
            for (int off = 1; off < 16; off <<= 1) {
                int y = __shfl_up(s, off, 64);
                if (lane >= off) s += y;
            }
            wsum[lane] = s;
        }
        __syncthreads();
        int wave_excl = (w == 0) ? 0 : wsum[w - 1];
        int excl = s_base + wave_excl + (x - v);
        if (i < N_NODES) { row_ptr[i] = excl; cursor[i] = excl; }
        __syncthreads();
        if (t == 0) s_base += wsum[15];
        __syncthreads();
    }
    if (t == 0) row_ptr[N_NODES] = s_base;
}

// ---------------------------------------------------------------------------
// 4) scatter edges into CSR slots
// ---------------------------------------------------------------------------
__global__ void scatter_kernel(const int* __restrict__ src, const int* __restrict__ dst,
                               int* __restrict__ cursor, int* __restrict__ csr_src) {
    int e = blockIdx.x * blockDim.x + threadIdx.x;
    if (e < E_EDGES) {
        int pos = atomicAdd(&cursor[dst[e]], 1);
        csr_src[pos] = src[e];
    }
}

// ---------------------------------------------------------------------------
// 5) W -> bf16 MFMA B-fragment layout, once per layer.
//    Layout: frag[(ks*8+ct)*64 + lane] = 8 bf16, element j = W[r][c],
//    r = ks*32 + (lane>>4)*8 + j (0..255 spans [Wself; Wneigh]), c = ct*16 + (lane&15)
// ---------------------------------------------------------------------------
__global__ void prep_w_kernel(const float* __restrict__ W1s, const float* __restrict__ W1n,
                              const float* __restrict__ W2s, const float* __restrict__ W2n,
                              uint4* __restrict__ wf1, uint4* __restrict__ wf2) {
    int tid = blockIdx.x * blockDim.x + threadIdx.x;   // 0..8191
    int layer = tid >> 12;
    int rem = tid & 4095;
    int ks = rem >> 9;
    int ct = (rem >> 6) & 7;
    int lane = rem & 63;
    const float* Ws = layer ? W2s : W1s;
    const float* Wn = layer ? W2n : W1n;
    uint4* outp = layer ? wf2 : wf1;
    int r0 = ks * 32 + (lane >> 4) * 8;
    int c = ct * 16 + (lane & 15);
    unsigned short e[8];
#pragma unroll
    for (int j = 0; j < 8; ++j) {
        int r = r0 + j;
        float v = (r < 128) ? Ws[r * 128 + c] : Wn[(r - 128) * 128 + c];
        e[j] = f2b(v);
    }
    uint4 o;
    o.x = (unsigned int)e[0] | ((unsigned int)e[1] << 16);
    o.y = (unsigned int)e[2] | ((unsigned int)e[3] << 16);
    o.z = (unsigned int)e[4] | ((unsigned int)e[5] << 16);
    o.w = (unsigned int)e[6] | ((unsigned int)e[7] << 16);
    outp[(ks * 8 + ct) * 64 + lane] = o;
}

// ---------------------------------------------------------------------------
// 6) gather-aggregate (bf16 in, f32 acc, bf16 out): aggb[n] = mean h[neigh]
// ---------------------------------------------------------------------------
__global__ void gather_agg_kernel(const int* __restrict__ row_ptr,
                                  const int* __restrict__ csr_src,
                                  const unsigned short* __restrict__ hb,
                                  unsigned short* __restrict__ aggb) {
    int idx = blockIdx.x * blockDim.x + threadIdx.x;
    int n = idx >> 4, q = idx & 15;
    if (n >= N_NODES) return;
    int beg = row_ptr[n], end = row_ptr[n + 1];
    float acc[8];
#pragma unroll
    for (int j = 0; j < 8; ++j) acc[j] = 0.f;
    for (int p = beg; p < end; ++p) {
        int s = csr_src[p];
        uint4 v = *reinterpret_cast<const uint4*>(hb + (size_t)s * D + q * 8);
        acc[0] += b2f((unsigned short)(v.x & 0xffff)); acc[1] += b2f((unsigned short)(v.x >> 16));
        acc[2] += b2f((unsigned short)(v.y & 0xffff)); acc[3] += b2f((unsigned short)(v.y >> 16));
        acc[4] += b2f((unsigned short)(v.z & 0xffff)); acc[5] += b2f((unsigned short)(v.z >> 16));
        acc[6] += b2f((unsigned short)(v.w & 0xffff)); acc[7] += b2f((unsigned short)(v.w >> 16));
    }
    int dcount = end - beg;
    float inv = 1.0f / (float)(dcount > 1 ? dcount : 1);
    uint4 o;
    o.x = (unsigned int)f2b(acc[0] * inv) | ((unsigned int)f2b(acc[1] * inv) << 16);
    o.y = (unsigned int)f2b(acc[2] * inv) | ((unsigned int)f2b(acc[3] * inv) << 16);
    o.z = (unsigned int)f2b(acc[4] * inv) | ((unsigned int)f2b(acc[5] * inv) << 16);
    o.w = (unsigned int)f2b(acc[6] * inv) | ((unsigned int)f2b(acc[7] * inv) << 16);
    *reinterpret_cast<uint4*>(aggb + (size_t)n * D + q * 8) = o;
}

// ---------------------------------------------------------------------------
// 7) out = [h | agg] @ [Ws; Wn] + b  via mfma_f32_16x16x32_bf16.
//    4 waves/block, wave = one 16-row tile x 128 cols (8 col-tiles, 8 k-steps).
//    In-place (outp==hb, layer 1) is safe: each wave loads only its own 16
//    rows up-front (data-dep before stores); waves/blocks own disjoint rows.
//    NOTE: no __restrict__ — outp aliases hb in layer 1.
// ---------------------------------------------------------------------------
template <int RELU, typename OutT>
__global__ __launch_bounds__(256, 2)
void linear_mfma_kernel(const unsigned short* hb, const unsigned short* aggb,
                        const uint4* wfrag, const float* bias, OutT* outp) {
    __shared__ uint4 wlds[4096];   // 64 KB
    int t = threadIdx.x;
#pragma unroll
    for (int i = 0; i < 16; ++i) wlds[t + i * 256] = wfrag[t + i * 256];
    __syncthreads();
    int lane = t & 63, w = t >> 6;
    int rt = blockIdx.x * 4 + w;
    if (rt >= NTILES) return;      // no barriers after this point
    int row0 = rt * 16;
    int arow = row0 + (lane & 15);
    int koff = (lane >> 4) * 8;
    const unsigned short* hp = hb + (size_t)arow * D + koff;
    const unsigned short* ap = aggb + (size_t)arow * D + koff;
    bf16x8 a[8];
#pragma unroll
    for (int ks = 0; ks < 4; ++ks) a[ks] = *reinterpret_cast<const bf16x8*>(hp + ks * 32);
#pragma unroll
    for (int ks = 0; ks < 4; ++ks) a[4 + ks] = *reinterpret_cast<const bf16x8*>(ap + ks * 32);
    int crow = row0 + (lane >> 4) * 4;
    int ccol0 = lane & 15;
#pragma unroll
    for (int ct = 0; ct < 8; ++ct) {
        f32x4 acc = {0.f, 0.f, 0.f, 0.f};
#pragma unroll
        for (int ks = 0; ks < 8; ++ks) {
            bf16x8 b = *reinterpret_cast<const bf16x8*>(&wlds[(ks * 8 + ct) * 64 + lane]);
            acc = __builtin_amdgcn_mfma_f32_16x16x32_bf16(a[ks], b, acc, 0, 0, 0);
        }
        int col = ct * 16 + ccol0;
        float bv = bias[col];
#pragma unroll
        for (int i = 0; i < 4; ++i) {
            float v = acc[i] + bv;
            if (RELU) v = (v > 0.f) ? v : NEG_SLOPE * v;
            if constexpr (sizeof(OutT) == 2) {
                outp[(size_t)(crow + i) * D + col] = (OutT)f2b(v);
            } else {
                outp[(size_t)(crow + i) * D + col] = v;
            }
        }
    }
}

extern "C" void kernel_launch(void* const* d_in, const int* in_sizes, int n_in,
                              void* d_out, int out_size, void* d_ws, size_t ws_size,
                              hipStream_t stream) {
    const int*   wids     = (const int*)d_in[0];
    const float* lengths  = (const float*)d_in[1];
    const int*   src      = (const int*)d_in[2];
    const int*   dst      = (const int*)d_in[3];
    const float* word_emb = (const float*)d_in[4];
    const float* W1s      = (const float*)d_in[5];
    const float* W1n      = (const float*)d_in[6];
    const float* b1       = (const float*)d_in[7];
    const float* W2s      = (const float*)d_in[8];
    const float* W2n      = (const float*)d_in[9];
    const float* b2       = (const float*)d_in[10];

    // workspace layout (all 16B-aligned by construction)
    unsigned short* h0  = (unsigned short*)d_ws;               // N*D bf16
    unsigned short* agg = h0 + (size_t)N_NODES * D;            // N*D bf16
    uint4* wf1 = (uint4*)(agg + (size_t)N_NODES * D);          // 4096 uint4 (64 KB)
    uint4* wf2 = wf1 + 4096;                                   // 4096 uint4
    int* deg_i   = (int*)(wf2 + 4096);                         // N
    int* row_ptr = deg_i + N_NODES;                            // N+1
    int* cursor  = row_ptr + (N_NODES + 1);                    // N
    int* csr_src = cursor + N_NODES;                           // E

    hipMemsetAsync(deg_i, 0, N_NODES * sizeof(int), stream);

    // pooled features (bf16)
    pool_kernel<<<(N_NODES * 32) / 256, 256, 0, stream>>>(wids, lengths, word_emb, h0);

    // CSR build (shared by both layers)
    degi_kernel<<<(E_EDGES + 255) / 256, 256, 0, stream>>>(dst, deg_i);
    scan_kernel<<<1, 1024, 0, stream>>>(deg_i, row_ptr, cursor);
    scatter_kernel<<<(E_EDGES + 255) / 256, 256, 0, stream>>>(src, dst, cursor, csr_src);

    // W fragments (both layers)
    prep_w_kernel<<<32, 256, 0, stream>>>(W1s, W1n, W2s, W2n, wf1, wf2);

    const int LIN_GRID = (NTILES + 3) / 4;  // 1594
    // layer 1 (in-place h0 -> h0)
    gather_agg_kernel<<<(N_NODES * 16) / 256, 256, 0, stream>>>(row_ptr, csr_src, h0, agg);
    linear_mfma_kernel<1, unsigned short><<<LIN_GRID, 256, 0, stream>>>(h0, agg, wf1, b1, h0);
    // layer 2 (f32 out)
    gather_agg_kernel<<<(N_NODES * 16) / 256, 256, 0, stream>>>(row_ptr, csr_src, h0, agg);
    linear_mfma_kernel<0, float><<<LIN_GRID, 256, 0, stream>>>(h0, agg, wf2, b2, (float*)d_out);
}

// Round 5
// 340.104 us; speedup vs baseline: 12.8666x; 1.2754x over previous
//
#include <hip/hip_runtime.h>

#define N_NODES 102000
#define D 128
#define L 12
#define E_EDGES 1000000
#define NEG_SLOPE 0.01f
#define NTILES (N_NODES / 16)   // 6375 exact (N % 16 == 0)

#define SCAN_CHUNK 1024
#define SCAN_BLOCKS ((N_NODES + SCAN_CHUNK - 1) / SCAN_CHUNK)  // 100

typedef __attribute__((ext_vector_type(8))) short bf16x8;
typedef __attribute__((ext_vector_type(4))) float f32x4;

__device__ __forceinline__ float b2f(unsigned short u) {
    union { float f; unsigned int i; } x; x.i = ((unsigned int)u) << 16; return x.f;
}
// round-to-nearest-even f32 -> bf16
__device__ __forceinline__ unsigned short f2b(float f) {
    unsigned int x = __float_as_uint(f);
    unsigned int r = (x + 0x7fffu + ((x >> 16) & 1u)) >> 16;
    return (unsigned short)r;
}

// ---------------------------------------------------------------------------
// 1) h[n] = sum_l word_emb[wids[n][l]] / lengths[n]   (f32 acc -> bf16 store)
// ---------------------------------------------------------------------------
__global__ void pool_kernel(const int* __restrict__ wids,
                            const float* __restrict__ lengths,
                            const float* __restrict__ word_emb,
                            unsigned short* __restrict__ hb) {
    int idx = blockIdx.x * blockDim.x + threadIdx.x;
    int n = idx >> 5, q = idx & 31;
    if (n >= N_NODES) return;
    const int* w = wids + n * L;
    float4 acc = make_float4(0.f, 0.f, 0.f, 0.f);
#pragma unroll
    for (int l = 0; l < L; ++l) {
        int wid = w[l];
        const float4 v = *reinterpret_cast<const float4*>(word_emb + (size_t)wid * D + q * 4);
        acc.x += v.x; acc.y += v.y; acc.z += v.z; acc.w += v.w;
    }
    float inv = 1.0f / lengths[n];
    ushort4 o;
    o.x = f2b(acc.x * inv); o.y = f2b(acc.y * inv);
    o.z = f2b(acc.z * inv); o.w = f2b(acc.w * inv);
    *reinterpret_cast<ushort4*>(hb + (size_t)n * D + q * 4) = o;
}

// ---------------------------------------------------------------------------
// 2) int degree histogram
// ---------------------------------------------------------------------------
__global__ void degi_kernel(const int* __restrict__ dst, int* __restrict__ deg) {
    int e = blockIdx.x * blockDim.x + threadIdx.x;
    if (e < E_EDGES) atomicAdd(&deg[dst[e]], 1);
}

// ---------------------------------------------------------------------------
// 3a) per-block local exclusive scan (1024 elems / block, 4 per thread)
//     writes local scan into row_ptr[], block total into block_sums[]
// ---------------------------------------------------------------------------
__global__ __launch_bounds__(256)
void scan_local_kernel(const int* __restrict__ deg, int* __restrict__ row_ptr,
                       int* __restrict__ block_sums) {
    __shared__ int wsum[4];
    int t = threadIdx.x;
    int lane = t & 63, w = t >> 6;
    int base = blockIdx.x * SCAN_CHUNK + t * 4;
    int v0 = 0, v1 = 0, v2 = 0, v3 = 0;
    if (base + 3 < N_NODES) {
        int4 v = *reinterpret_cast<const int4*>(deg + base);
        v0 = v.x; v1 = v.y; v2 = v.z; v3 = v.w;
    } else {
        if (base + 0 < N_NODES) v0 = deg[base + 0];
        if (base + 1 < N_NODES) v1 = deg[base + 1];
        if (base + 2 < N_NODES) v2 = deg[base + 2];
        if (base + 3 < N_NODES) v3 = deg[base + 3];
    }
    int s = v0 + v1 + v2 + v3;
    int x = s;
#pragma unroll
    for (int off = 1; off < 64; off <<= 1) {
        int y = __shfl_up(x, off, 64);
        if (lane >= off) x += y;
    }
    if (lane == 63) wsum[w] = x;
    __syncthreads();
    int woff = 0;
#pragma unroll
    for (int i = 0; i < 4; ++i) if (i < w) woff += wsum[i];
    int excl = woff + (x - s);
    if (base + 0 < N_NODES) row_ptr[base + 0] = excl;
    if (base + 1 < N_NODES) row_ptr[base + 1] = excl + v0;
    if (base + 2 < N_NODES) row_ptr[base + 2] = excl + v0 + v1;
    if (base + 3 < N_NODES) row_ptr[base + 3] = excl + v0 + v1 + v2;
    if (t == 0) block_sums[blockIdx.x] = 0;  // ensure defined, overwritten below
    __syncthreads();
    if (t == 255) block_sums[blockIdx.x] = woff + x;  // total of this block
}

// ---------------------------------------------------------------------------
// 3b) exclusive scan of the 100 block sums (one wave, 2 elems/lane)
// ---------------------------------------------------------------------------
__global__ __launch_bounds__(64)
void scan_blocks_kernel(int* __restrict__ block_sums, int* __restrict__ row_ptr) {
    int lane = threadIdx.x;
    int e0 = (2 * lane + 0 < SCAN_BLOCKS) ? block_sums[2 * lane + 0] : 0;
    int e1 = (2 * lane + 1 < SCAN_BLOCKS) ? block_sums[2 * lane + 1] : 0;
    int s = e0 + e1;
    int x = s;
#pragma unroll
    for (int off = 1; off < 64; off <<= 1) {
        int y = __shfl_up(x, off, 64);
        if (lane >= off) x += y;
    }
    int excl = x - s;
    if (2 * lane + 0 < SCAN_BLOCKS) block_sums[2 * lane + 0] = excl;
    if (2 * lane + 1 < SCAN_BLOCKS) block_sums[2 * lane + 1] = excl + e0;
    if (lane == 63) row_ptr[N_NODES] = x;   // total = E_EDGES
}

// ---------------------------------------------------------------------------
// 3c) add block offsets; emit final row_ptr and cursor copy
// ---------------------------------------------------------------------------
__global__ __launch_bounds__(256)
void scan_fixup_kernel(int* __restrict__ row_ptr, const int* __restrict__ block_sums,
                       int* __restrict__ cursor) {
    int base = blockIdx.x * SCAN_CHUNK + threadIdx.x * 4;
    int boff = block_sums[blockIdx.x];
#pragma unroll
    for (int j = 0; j < 4; ++j) {
        int i = base + j;
        if (i < N_NODES) {
            int v = row_ptr[i] + boff;
            row_ptr[i] = v;
            cursor[i] = v;
        }
    }
}

// ---------------------------------------------------------------------------
// 4) scatter edges into CSR slots
// ---------------------------------------------------------------------------
__global__ void scatter_kernel(const int* __restrict__ src, const int* __restrict__ dst,
                               int* __restrict__ cursor, int* __restrict__ csr_src) {
    int e = blockIdx.x * blockDim.x + threadIdx.x;
    if (e < E_EDGES) {
        int pos = atomicAdd(&cursor[dst[e]], 1);
        csr_src[pos] = src[e];
    }
}

// ---------------------------------------------------------------------------
// 5) W -> bf16 MFMA B-fragment layout, once per layer.
// ---------------------------------------------------------------------------
__global__ void prep_w_kernel(const float* __restrict__ W1s, const float* __restrict__ W1n,
                              const float* __restrict__ W2s, const float* __restrict__ W2n,
                              uint4* __restrict__ wf1, uint4* __restrict__ wf2) {
    int tid = blockIdx.x * blockDim.x + threadIdx.x;   // 0..8191
    int layer = tid >> 12;
    int rem = tid & 4095;
    int ks = rem >> 9;
    int ct = (rem >> 6) & 7;
    int lane = rem & 63;
    const float* Ws = layer ? W2s : W1s;
    const float* Wn = layer ? W2n : W1n;
    uint4* outp = layer ? wf2 : wf1;
    int r0 = ks * 32 + (lane >> 4) * 8;
    int c = ct * 16 + (lane & 15);
    unsigned short e[8];
#pragma unroll
    for (int j = 0; j < 8; ++j) {
        int r = r0 + j;
        float v = (r < 128) ? Ws[r * 128 + c] : Wn[(r - 128) * 128 + c];
        e[j] = f2b(v);
    }
    uint4 o;
    o.x = (unsigned int)e[0] | ((unsigned int)e[1] << 16);
    o.y = (unsigned int)e[2] | ((unsigned int)e[3] << 16);
    o.z = (unsigned int)e[4] | ((unsigned int)e[5] << 16);
    o.w = (unsigned int)e[6] | ((unsigned int)e[7] << 16);
    outp[(ks * 8 + ct) * 64 + lane] = o;
}

// ---------------------------------------------------------------------------
// 6) gather-aggregate (bf16 in, f32 acc, bf16 out): aggb[n] = mean h[neigh]
// ---------------------------------------------------------------------------
__global__ void gather_agg_kernel(const int* __restrict__ row_ptr,
                                  const int* __restrict__ csr_src,
                                  const unsigned short* __restrict__ hb,
                                  unsigned short* __restrict__ aggb) {
    int idx = blockIdx.x * blockDim.x + threadIdx.x;
    int n = idx >> 4, q = idx & 15;
    if (n >= N_NODES) return;
    int beg = row_ptr[n], end = row_ptr[n + 1];
    float acc[8];
#pragma unroll
    for (int j = 0; j < 8; ++j) acc[j] = 0.f;
    for (int p = beg; p < end; ++p) {
        int s = csr_src[p];
        uint4 v = *reinterpret_cast<const uint4*>(hb + (size_t)s * D + q * 8);
        acc[0] += b2f((unsigned short)(v.x & 0xffff)); acc[1] += b2f((unsigned short)(v.x >> 16));
        acc[2] += b2f((unsigned short)(v.y & 0xffff)); acc[3] += b2f((unsigned short)(v.y >> 16));
        acc[4] += b2f((unsigned short)(v.z & 0xffff)); acc[5] += b2f((unsigned short)(v.z >> 16));
        acc[6] += b2f((unsigned short)(v.w & 0xffff)); acc[7] += b2f((unsigned short)(v.w >> 16));
    }
    int dcount = end - beg;
    float inv = 1.0f / (float)(dcount > 1 ? dcount : 1);
    uint4 o;
    o.x = (unsigned int)f2b(acc[0] * inv) | ((unsigned int)f2b(acc[1] * inv) << 16);
    o.y = (unsigned int)f2b(acc[2] * inv) | ((unsigned int)f2b(acc[3] * inv) << 16);
    o.z = (unsigned int)f2b(acc[4] * inv) | ((unsigned int)f2b(acc[5] * inv) << 16);
    o.w = (unsigned int)f2b(acc[6] * inv) | ((unsigned int)f2b(acc[7] * inv) << 16);
    *reinterpret_cast<uint4*>(aggb + (size_t)n * D + q * 8) = o;
}

// ---------------------------------------------------------------------------
// 7) out = [h | agg] @ [Ws; Wn] + b  via mfma_f32_16x16x32_bf16.
//    4 waves/block, wave = one 16-row tile x 128 cols.
//    In-place (outp==hb, layer 1) is safe: each wave loads only its own 16
//    rows up-front; waves/blocks own disjoint rows. No __restrict__ (aliasing).
// ---------------------------------------------------------------------------
template <int RELU, typename OutT>
__global__ __launch_bounds__(256, 2)
void linear_mfma_kernel(const unsigned short* hb, const unsigned short* aggb,
                        const uint4* wfrag, const float* bias, OutT* outp) {
    __shared__ uint4 wlds[4096];   // 64 KB
    int t = threadIdx.x;
#pragma unroll
    for (int i = 0; i < 16; ++i) wlds[t + i * 256] = wfrag[t + i * 256];
    __syncthreads();
    int lane = t & 63, w = t >> 6;
    int rt = blockIdx.x * 4 + w;
    if (rt >= NTILES) return;      // no barriers after this point
    int row0 = rt * 16;
    int arow = row0 + (lane & 15);
    int koff = (lane >> 4) * 8;
    const unsigned short* hp = hb + (size_t)arow * D + koff;
    const unsigned short* ap = aggb + (size_t)arow * D + koff;
    bf16x8 a[8];
#pragma unroll
    for (int ks = 0; ks < 4; ++ks) a[ks] = *reinterpret_cast<const bf16x8*>(hp + ks * 32);
#pragma unroll
    for (int ks = 0; ks < 4; ++ks) a[4 + ks] = *reinterpret_cast<const bf16x8*>(ap + ks * 32);
    int crow = row0 + (lane >> 4) * 4;
    int ccol0 = lane & 15;
#pragma unroll
    for (int ct = 0; ct < 8; ++ct) {
        f32x4 acc = {0.f, 0.f, 0.f, 0.f};
#pragma unroll
        for (int ks = 0; ks < 8; ++ks) {
            bf16x8 b = *reinterpret_cast<const bf16x8*>(&wlds[(ks * 8 + ct) * 64 + lane]);
            acc = __builtin_amdgcn_mfma_f32_16x16x32_bf16(a[ks], b, acc, 0, 0, 0);
        }
        int col = ct * 16 + ccol0;
        float bv = bias[col];
#pragma unroll
        for (int i = 0; i < 4; ++i) {
            float v = acc[i] + bv;
            if (RELU) v = (v > 0.f) ? v : NEG_SLOPE * v;
            if constexpr (sizeof(OutT) == 2) {
                outp[(size_t)(crow + i) * D + col] = (OutT)f2b(v);
            } else {
                outp[(size_t)(crow + i) * D + col] = v;
            }
        }
    }
}

extern "C" void kernel_launch(void* const* d_in, const int* in_sizes, int n_in,
                              void* d_out, int out_size, void* d_ws, size_t ws_size,
                              hipStream_t stream) {
    const int*   wids     = (const int*)d_in[0];
    const float* lengths  = (const float*)d_in[1];
    const int*   src      = (const int*)d_in[2];
    const int*   dst      = (const int*)d_in[3];
    const float* word_emb = (const float*)d_in[4];
    const float* W1s      = (const float*)d_in[5];
    const float* W1n      = (const float*)d_in[6];
    const float* b1       = (const float*)d_in[7];
    const float* W2s      = (const float*)d_in[8];
    const float* W2n      = (const float*)d_in[9];
    const float* b2       = (const float*)d_in[10];

    // workspace layout (all 16B-aligned by construction)
    unsigned short* h0  = (unsigned short*)d_ws;               // N*D bf16
    unsigned short* agg = h0 + (size_t)N_NODES * D;            // N*D bf16
    uint4* wf1 = (uint4*)(agg + (size_t)N_NODES * D);          // 4096 uint4 (64 KB)
    uint4* wf2 = wf1 + 4096;                                   // 4096 uint4
    int* deg_i      = (int*)(wf2 + 4096);                      // N
    int* row_ptr    = deg_i + N_NODES;                         // N+1
    int* cursor     = row_ptr + (N_NODES + 1);                 // N
    int* block_sums = cursor + N_NODES;                        // SCAN_BLOCKS
    int* csr_src    = block_sums + ((SCAN_BLOCKS + 3) & ~3);   // E

    hipMemsetAsync(deg_i, 0, N_NODES * sizeof(int), stream);

    // pooled features (bf16)
    pool_kernel<<<(N_NODES * 32) / 256, 256, 0, stream>>>(wids, lengths, word_emb, h0);

    // CSR build (shared by both layers)
    degi_kernel<<<(E_EDGES + 255) / 256, 256, 0, stream>>>(dst, deg_i);
    scan_local_kernel<<<SCAN_BLOCKS, 256, 0, stream>>>(deg_i, row_ptr, block_sums);
    scan_blocks_kernel<<<1, 64, 0, stream>>>(block_sums, row_ptr);
    scan_fixup_kernel<<<SCAN_BLOCKS, 256, 0, stream>>>(row_ptr, block_sums, cursor);
    scatter_kernel<<<(E_EDGES + 255) / 256, 256, 0, stream>>>(src, dst, cursor, csr_src);

    // W fragments (both layers)
    prep_w_kernel<<<32, 256, 0, stream>>>(W1s, W1n, W2s, W2n, wf1, wf2);

    const int LIN_GRID = (NTILES + 3) / 4;  // 1594
    // layer 1 (in-place h0 -> h0)
    gather_agg_kernel<<<(N_NODES * 16) / 256, 256, 0, stream>>>(row_ptr, csr_src, h0, agg);
    linear_mfma_kernel<1, unsigned short><<<LIN_GRID, 256, 0, stream>>>(h0, agg, wf1, b1, h0);
    // layer 2 (f32 out)
    gather_agg_kernel<<<(N_NODES * 16) / 256, 256, 0, stream>>>(row_ptr, csr_src, h0, agg);
    linear_mfma_kernel<0, float><<<LIN_GRID, 256, 0, stream>>>(h0, agg, wf2, b2, (float*)d_out);
}

// Round 6
// 317.049 us; speedup vs baseline: 13.8022x; 1.0727x over previous
//
#include <hip/hip_runtime.h>

#define N_NODES 102000
#define D 128
#define L 12
#define E_EDGES 1000000
#define NEG_SLOPE 0.01f
#define NTILES (N_NODES / 16)   // 6375 exact (N % 16 == 0)

#define SCAN_CHUNK 1024
#define SCAN_BLOCKS ((N_NODES + SCAN_CHUNK - 1) / SCAN_CHUNK)  // 100

#define NXCD 8
#define RANGE (N_NODES / NXCD)   // 12750 exact

typedef __attribute__((ext_vector_type(8))) short bf16x8;
typedef __attribute__((ext_vector_type(4))) float f32x4;

__device__ __forceinline__ float b2f(unsigned short u) {
    union { float f; unsigned int i; } x; x.i = ((unsigned int)u) << 16; return x.f;
}
// round-to-nearest-even f32 -> bf16
__device__ __forceinline__ unsigned short f2b(float f) {
    unsigned int x = __float_as_uint(f);
    unsigned int r = (x + 0x7fffu + ((x >> 16) & 1u)) >> 16;
    return (unsigned short)r;
}

// ---------------------------------------------------------------------------
// 1) h[n] = sum_l word_emb[wids[n][l]] / lengths[n]   (f32 acc -> bf16 store)
// ---------------------------------------------------------------------------
__global__ void pool_kernel(const int* __restrict__ wids,
                            const float* __restrict__ lengths,
                            const float* __restrict__ word_emb,
                            unsigned short* __restrict__ hb) {
    int idx = blockIdx.x * blockDim.x + threadIdx.x;
    int n = idx >> 5, q = idx & 31;
    if (n >= N_NODES) return;
    const int* w = wids + n * L;
    float4 acc = make_float4(0.f, 0.f, 0.f, 0.f);
#pragma unroll
    for (int l = 0; l < L; ++l) {
        int wid = w[l];
        const float4 v = *reinterpret_cast<const float4*>(word_emb + (size_t)wid * D + q * 4);
        acc.x += v.x; acc.y += v.y; acc.z += v.z; acc.w += v.w;
    }
    float inv = 1.0f / lengths[n];
    ushort4 o;
    o.x = f2b(acc.x * inv); o.y = f2b(acc.y * inv);
    o.z = f2b(acc.z * inv); o.w = f2b(acc.w * inv);
    *reinterpret_cast<ushort4*>(hb + (size_t)n * D + q * 4) = o;
}

// ---------------------------------------------------------------------------
// 2) degree histogram, XCD-range-partitioned: group g = blockIdx&7 handles
//    dst in [g*RANGE, (g+1)*RANGE) -> deg sub-array is written by one XCD only
// ---------------------------------------------------------------------------
#define DEGI_CHUNKS 256
__global__ void degi_kernel(const int* __restrict__ dst, int* __restrict__ deg) {
    int g = blockIdx.x & (NXCD - 1);
    int cb = blockIdx.x >> 3;              // 0..DEGI_CHUNKS-1
    int lo = g * RANGE, hi = lo + RANGE;
    const int stride = DEGI_CHUNKS * 256;
    for (int e = cb * 256 + threadIdx.x; e < E_EDGES; e += stride) {
        int d = dst[e];
        if (d >= lo && d < hi) atomicAdd(&deg[d], 1);
    }
}

// ---------------------------------------------------------------------------
// 3a) per-block local exclusive scan (1024 elems / block, 4 per thread)
// ---------------------------------------------------------------------------
__global__ __launch_bounds__(256)
void scan_local_kernel(const int* __restrict__ deg, int* __restrict__ row_ptr,
                       int* __restrict__ block_sums) {
    __shared__ int wsum[4];
    int t = threadIdx.x;
    int lane = t & 63, w = t >> 6;
    int base = blockIdx.x * SCAN_CHUNK + t * 4;
    int v0 = 0, v1 = 0, v2 = 0, v3 = 0;
    if (base + 3 < N_NODES) {
        int4 v = *reinterpret_cast<const int4*>(deg + base);
        v0 = v.x; v1 = v.y; v2 = v.z; v3 = v.w;
    } else {
        if (base + 0 < N_NODES) v0 = deg[base + 0];
        if (base + 1 < N_NODES) v1 = deg[base + 1];
        if (base + 2 < N_NODES) v2 = deg[base + 2];
        if (base + 3 < N_NODES) v3 = deg[base + 3];
    }
    int s = v0 + v1 + v2 + v3;
    int x = s;
#pragma unroll
    for (int off = 1; off < 64; off <<= 1) {
        int y = __shfl_up(x, off, 64);
        if (lane >= off) x += y;
    }
    if (lane == 63) wsum[w] = x;
    __syncthreads();
    int woff = 0;
#pragma unroll
    for (int i = 0; i < 4; ++i) if (i < w) woff += wsum[i];
    int excl = woff + (x - s);
    if (base + 0 < N_NODES) row_ptr[base + 0] = excl;
    if (base + 1 < N_NODES) row_ptr[base + 1] = excl + v0;
    if (base + 2 < N_NODES) row_ptr[base + 2] = excl + v0 + v1;
    if (base + 3 < N_NODES) row_ptr[base + 3] = excl + v0 + v1 + v2;
    __syncthreads();
    if (t == 255) block_sums[blockIdx.x] = woff + x;  // total of this block
}

// ---------------------------------------------------------------------------
// 3b) exclusive scan of the 100 block sums (one wave, 2 elems/lane)
// ---------------------------------------------------------------------------
__global__ __launch_bounds__(64)
void scan_blocks_kernel(int* __restrict__ block_sums, int* __restrict__ row_ptr) {
    int lane = threadIdx.x;
    int e0 = (2 * lane + 0 < SCAN_BLOCKS) ? block_sums[2 * lane + 0] : 0;
    int e1 = (2 * lane + 1 < SCAN_BLOCKS) ? block_sums[2 * lane + 1] : 0;
    int s = e0 + e1;
    int x = s;
#pragma unroll
    for (int off = 1; off < 64; off <<= 1) {
        int y = __shfl_up(x, off, 64);
        if (lane >= off) x += y;
    }
    int excl = x - s;
    if (2 * lane + 0 < SCAN_BLOCKS) block_sums[2 * lane + 0] = excl;
    if (2 * lane + 1 < SCAN_BLOCKS) block_sums[2 * lane + 1] = excl + e0;
    if (lane == 63) row_ptr[N_NODES] = x;   // total = E_EDGES
}

// ---------------------------------------------------------------------------
// 3c) add block offsets; emit final row_ptr and cursor copy
// ---------------------------------------------------------------------------
__global__ __launch_bounds__(256)
void scan_fixup_kernel(int* __restrict__ row_ptr, const int* __restrict__ block_sums,
                       int* __restrict__ cursor) {
    int base = blockIdx.x * SCAN_CHUNK + threadIdx.x * 4;
    int boff = block_sums[blockIdx.x];
#pragma unroll
    for (int j = 0; j < 4; ++j) {
        int i = base + j;
        if (i < N_NODES) {
            int v = row_ptr[i] + boff;
            row_ptr[i] = v;
            cursor[i] = v;
        }
    }
}

// ---------------------------------------------------------------------------
// 4) scatter edges into CSR slots, XCD-range-partitioned: group g commits
//    only dst in its range -> cursor atomics and csr_src writes are XCD-local
//    (L2-resident, single writeback) instead of 16x line-amplified to HBM.
//    Correct regardless of actual block->XCD mapping (each edge committed
//    exactly once).
// ---------------------------------------------------------------------------
#define SCAT_CHUNKS 512
__global__ void scatter_kernel(const int* __restrict__ src, const int* __restrict__ dst,
                               int* __restrict__ cursor, int* __restrict__ csr_src) {
    int g = blockIdx.x & (NXCD - 1);
    int cb = blockIdx.x >> 3;              // 0..SCAT_CHUNKS-1
    int lo = g * RANGE, hi = lo + RANGE;
    const int stride = SCAT_CHUNKS * 256;
    for (int e = cb * 256 + threadIdx.x; e < E_EDGES; e += stride) {
        int d = dst[e];
        if (d >= lo && d < hi) {
            int pos = atomicAdd(&cursor[d], 1);
            csr_src[pos] = src[e];
        }
    }
}

// ---------------------------------------------------------------------------
// 5) W -> bf16 MFMA B-fragment layout, once per layer.
// ---------------------------------------------------------------------------
__global__ void prep_w_kernel(const float* __restrict__ W1s, const float* __restrict__ W1n,
                              const float* __restrict__ W2s, const float* __restrict__ W2n,
                              uint4* __restrict__ wf1, uint4* __restrict__ wf2) {
    int tid = blockIdx.x * blockDim.x + threadIdx.x;   // 0..8191
    int layer = tid >> 12;
    int rem = tid & 4095;
    int ks = rem >> 9;
    int ct = (rem >> 6) & 7;
    int lane = rem & 63;
    const float* Ws = layer ? W2s : W1s;
    const float* Wn = layer ? W2n : W1n;
    uint4* outp = layer ? wf2 : wf1;
    int r0 = ks * 32 + (lane >> 4) * 8;
    int c = ct * 16 + (lane & 15);
    unsigned short e[8];
#pragma unroll
    for (int j = 0; j < 8; ++j) {
        int r = r0 + j;
        float v = (r < 128) ? Ws[r * 128 + c] : Wn[(r - 128) * 128 + c];
        e[j] = f2b(v);
    }
    uint4 o;
    o.x = (unsigned int)e[0] | ((unsigned int)e[1] << 16);
    o.y = (unsigned int)e[2] | ((unsigned int)e[3] << 16);
    o.z = (unsigned int)e[4] | ((unsigned int)e[5] << 16);
    o.w = (unsigned int)e[6] | ((unsigned int)e[7] << 16);
    outp[(ks * 8 + ct) * 64 + lane] = o;
}

// ---------------------------------------------------------------------------
// 6) gather-aggregate (bf16 in, f32 acc, bf16 out): aggb[n] = mean h[neigh]
// ---------------------------------------------------------------------------
__global__ void gather_agg_kernel(const int* __restrict__ row_ptr,
                                  const int* __restrict__ csr_src,
                                  const unsigned short* __restrict__ hb,
                                  unsigned short* __restrict__ aggb) {
    int idx = blockIdx.x * blockDim.x + threadIdx.x;
    int n = idx >> 4, q = idx & 15;
    if (n >= N_NODES) return;
    int beg = row_ptr[n], end = row_ptr[n + 1];
    float acc[8];
#pragma unroll
    for (int j = 0; j < 8; ++j) acc[j] = 0.f;
    for (int p = beg; p < end; ++p) {
        int s = csr_src[p];
        uint4 v = *reinterpret_cast<const uint4*>(hb + (size_t)s * D + q * 8);
        acc[0] += b2f((unsigned short)(v.x & 0xffff)); acc[1] += b2f((unsigned short)(v.x >> 16));
        acc[2] += b2f((unsigned short)(v.y & 0xffff)); acc[3] += b2f((unsigned short)(v.y >> 16));
        acc[4] += b2f((unsigned short)(v.z & 0xffff)); acc[5] += b2f((unsigned short)(v.z >> 16));
        acc[6] += b2f((unsigned short)(v.w & 0xffff)); acc[7] += b2f((unsigned short)(v.w >> 16));
    }
    int dcount = end - beg;
    float inv = 1.0f / (float)(dcount > 1 ? dcount : 1);
    uint4 o;
    o.x = (unsigned int)f2b(acc[0] * inv) | ((unsigned int)f2b(acc[1] * inv) << 16);
    o.y = (unsigned int)f2b(acc[2] * inv) | ((unsigned int)f2b(acc[3] * inv) << 16);
    o.z = (unsigned int)f2b(acc[4] * inv) | ((unsigned int)f2b(acc[5] * inv) << 16);
    o.w = (unsigned int)f2b(acc[6] * inv) | ((unsigned int)f2b(acc[7] * inv) << 16);
    *reinterpret_cast<uint4*>(aggb + (size_t)n * D + q * 8) = o;
}

// ---------------------------------------------------------------------------
// 7) out = [h | agg] @ [Ws; Wn] + b  via mfma_f32_16x16x32_bf16.
//    4 waves/block, wave = one 16-row tile x 128 cols.
//    In-place (outp==hb, layer 1) is safe: each wave loads only its own 16
//    rows up-front; waves/blocks own disjoint rows. No __restrict__ (aliasing).
// ---------------------------------------------------------------------------
template <int RELU, typename OutT>
__global__ __launch_bounds__(256, 2)
void linear_mfma_kernel(const unsigned short* hb, const unsigned short* aggb,
                        const uint4* wfrag, const float* bias, OutT* outp) {
    __shared__ uint4 wlds[4096];   // 64 KB
    int t = threadIdx.x;
#pragma unroll
    for (int i = 0; i < 16; ++i) wlds[t + i * 256] = wfrag[t + i * 256];
    __syncthreads();
    int lane = t & 63, w = t >> 6;
    int rt = blockIdx.x * 4 + w;
    if (rt >= NTILES) return;      // no barriers after this point
    int row0 = rt * 16;
    int arow = row0 + (lane & 15);
    int koff = (lane >> 4) * 8;
    const unsigned short* hp = hb + (size_t)arow * D + koff;
    const unsigned short* ap = aggb + (size_t)arow * D + koff;
    bf16x8 a[8];
#pragma unroll
    for (int ks = 0; ks < 4; ++ks) a[ks] = *reinterpret_cast<const bf16x8*>(hp + ks * 32);
#pragma unroll
    for (int ks = 0; ks < 4; ++ks) a[4 + ks] = *reinterpret_cast<const bf16x8*>(ap + ks * 32);
    int crow = row0 + (lane >> 4) * 4;
    int ccol0 = lane & 15;
#pragma unroll
    for (int ct = 0; ct < 8; ++ct) {
        f32x4 acc = {0.f, 0.f, 0.f, 0.f};
#pragma unroll
        for (int ks = 0; ks < 8; ++ks) {
            bf16x8 b = *reinterpret_cast<const bf16x8*>(&wlds[(ks * 8 + ct) * 64 + lane]);
            acc = __builtin_amdgcn_mfma_f32_16x16x32_bf16(a[ks], b, acc, 0, 0, 0);
        }
        int col = ct * 16 + ccol0;
        float bv = bias[col];
#pragma unroll
        for (int i = 0; i < 4; ++i) {
            float v = acc[i] + bv;
            if (RELU) v = (v > 0.f) ? v : NEG_SLOPE * v;
            if constexpr (sizeof(OutT) == 2) {
                outp[(size_t)(crow + i) * D + col] = (OutT)f2b(v);
            } else {
                outp[(size_t)(crow + i) * D + col] = v;
            }
        }
    }
}

extern "C" void kernel_launch(void* const* d_in, const int* in_sizes, int n_in,
                              void* d_out, int out_size, void* d_ws, size_t ws_size,
                              hipStream_t stream) {
    const int*   wids     = (const int*)d_in[0];
    const float* lengths  = (const float*)d_in[1];
    const int*   src      = (const int*)d_in[2];
    const int*   dst      = (const int*)d_in[3];
    const float* word_emb = (const float*)d_in[4];
    const float* W1s      = (const float*)d_in[5];
    const float* W1n      = (const float*)d_in[6];
    const float* b1       = (const float*)d_in[7];
    const float* W2s      = (const float*)d_in[8];
    const float* W2n      = (const float*)d_in[9];
    const float* b2       = (const float*)d_in[10];

    // workspace layout (all 16B-aligned by construction)
    unsigned short* h0  = (unsigned short*)d_ws;               // N*D bf16
    unsigned short* agg = h0 + (size_t)N_NODES * D;            // N*D bf16
    uint4* wf1 = (uint4*)(agg + (size_t)N_NODES * D);          // 4096 uint4 (64 KB)
    uint4* wf2 = wf1 + 4096;                                   // 4096 uint4
    int* deg_i      = (int*)(wf2 + 4096);                      // N
    int* row_ptr    = deg_i + N_NODES;                         // N+1
    int* cursor     = row_ptr + (N_NODES + 1);                 // N
    int* block_sums = cursor + N_NODES;                        // SCAN_BLOCKS
    int* csr_src    = block_sums + ((SCAN_BLOCKS + 3) & ~3);   // E

    hipMemsetAsync(deg_i, 0, N_NODES * sizeof(int), stream);

    // pooled features (bf16)
    pool_kernel<<<(N_NODES * 32) / 256, 256, 0, stream>>>(wids, lengths, word_emb, h0);

    // CSR build (shared by both layers)
    degi_kernel<<<NXCD * DEGI_CHUNKS, 256, 0, stream>>>(dst, deg_i);
    scan_local_kernel<<<SCAN_BLOCKS, 256, 0, stream>>>(deg_i, row_ptr, block_sums);
    scan_blocks_kernel<<<1, 64, 0, stream>>>(block_sums, row_ptr);
    scan_fixup_kernel<<<SCAN_BLOCKS, 256, 0, stream>>>(row_ptr, block_sums, cursor);
    scatter_kernel<<<NXCD * SCAT_CHUNKS, 256, 0, stream>>>(src, dst, cursor, csr_src);

    // W fragments (both layers)
    prep_w_kernel<<<32, 256, 0, stream>>>(W1s, W1n, W2s, W2n, wf1, wf2);

    const int LIN_GRID = (NTILES + 3) / 4;  // 1594
    // layer 1 (in-place h0 -> h0)
    gather_agg_kernel<<<(N_NODES * 16) / 256, 256, 0, stream>>>(row_ptr, csr_src, h0, agg);
    linear_mfma_kernel<1, unsigned short><<<LIN_GRID, 256, 0, stream>>>(h0, agg, wf1, b1, h0);
    // layer 2 (f32 out)
    gather_agg_kernel<<<(N_NODES * 16) / 256, 256, 0, stream>>>(row_ptr, csr_src, h0, agg);
    linear_mfma_kernel<0, float><<<LIN_GRID, 256, 0, stream>>>(h0, agg, wf2, b2, (float*)d_out);
}